// Round 11
// baseline (131.571 us; speedup 1.0000x reference)
//
#include <hip/hip_runtime.h>
#include <math.h>

#define HH 512
#define WW 512
#define HWSZ (HH * WW)          // 262144
#define NB 4
#define NPIX (NB * HWSZ)        // 1048576
#define TMAX 16

#define CAP 131072              // dense component capacity (observed n_comp ~70k)
#define NPART 24                // padded partials row (21 used)
#define NBLK 1024               // pixel-pass blocks (4 px/thread)
#define SMB 256                 // scanmins blocks; each covers 512 dense comps
#define RSTRIDE 20              // interD row stride in ints (80 B; 17 used)
#define FLAGBIT 0x80000000u
#define POLLCAP (1 << 22)

// two-level CC: 32x32 tiles, 16 tiles/row, 256 tiles/img, 1024 blocks
#define TS 32
#define SEAMS 15
#define EDGES_PER_DIR (NB * SEAMS * HH)   // 30720
#define NEDGES (2 * EDGES_PER_DIR)        // 61440
#define BORDER_BLOCKS 64

struct Scalars {
  double sums[4];               // bce, sum_p, sum_pt, sum_t
  int cnt_t[TMAX + 1];
  int n_comp;
};

__device__ __forceinline__ float pair_loss(float cp, float it, float ctf) {
  const float Nf = (float)NPIX;
  float bce = (Nf * 0.69314718f + cp * 0.62011451f - it) / Nf;  // SP0, SP1-SP0
  float sum_pt = 0.5f * ctf + 0.23105858f * it;                 // S1-0.5
  float sum_p = 0.5f * Nf + 0.23105858f * cp;
  float dice = 1.0f - (2.0f * sum_pt + 1.0f) / (sum_p + ctf + 1.0f);
  return bce + dice;            // always > 0 -> float bits order == value order
}

// ---- union-find (max-root) with path-halving ----
__device__ __forceinline__ int chaseRO(const int* __restrict__ P, int x) {
  int p = P[x];
  while (p != x) { x = p; p = P[x]; }
  return x;
}
__device__ __forceinline__ int findRootH(int* P, int x) {
  int p = P[x];
  while (p != x) {
    int gp = P[p];
    if (gp == p) return p;
    P[x] = gp;
    x = gp; p = P[x];
  }
  return x;
}
__device__ void unite(int* P, int a, int b) {
  a = findRootH(P, a);
  b = findRootH(P, b);
  for (;;) {
    if (a == b) return;
    if (a > b) { int t = a; a = b; b = t; }
    int old = atomicMax(&P[a], b);
    if (old == a) return;
    a = findRootH(P, old);
    b = findRootH(P, b);
  }
}
__device__ __forceinline__ int findL(const int* lp, int x) {
  int p = lp[x];
  while (p != x) { x = p; p = lp[x]; }
  return x;
}
__device__ void uniteL(int* lp, int a, int b) {
  a = findL(lp, a);
  b = findL(lp, b);
  for (;;) {
    if (a == b) return;
    if (a > b) { int t = a; a = b; b = t; }
    int old = atomicMax(&lp[a], b);
    if (old == a) return;
    a = findL(lp, old);
    b = findL(lp, b);
  }
}

// ---- k_tile: fused init + per-tile 32x32 LDS CC; zero lookback state ----
__global__ __launch_bounds__(256) void k_tile(const float* __restrict__ pred,
                                              const int* __restrict__ tgt,
                                              int* __restrict__ P,
                                              double* __restrict__ part,
                                              unsigned* __restrict__ state) {
  __shared__ int lp[TS * TS];
  __shared__ int hist[TMAX + 1];
  __shared__ double red[4][4];
  int tid = threadIdx.x, bid = blockIdx.x;
  if (!tid) state[bid] = 0;
  if (tid <= TMAX) hist[tid] = 0;
  int b = bid >> 8;
  int ty = (bid >> 4) & 15, tx = bid & 15;
  int gbase = b * HWSZ + ((ty << 5) << 9) + (tx << 5);
  int c0 = tid << 2;
  int hw0 = (gbase - b * HWSZ) + ((c0 >> 5) << 9) + (c0 & 31);
  int gi0 = b * HWSZ + hw0;
  const float* pb = pred + ((size_t)(b << 1)) * HWSZ;
  float4 p0 = *(const float4*)(pb + hw0);
  float4 p1 = *(const float4*)(pb + HWSZ + hw0);
  int4 tv = *(const int4*)(tgt + gi0);
  __syncthreads();

  float s0 = 0.f, s1 = 0.f, s2 = 0.f, s3 = 0.f;
#define ELEM(P0, P1, TV, K)                                      \
  {                                                              \
    bool fg = (P1) > (P0);                                       \
    float logit = fg ? (P1) : 0.0f;                              \
    float tb = ((TV) > 0) ? 1.0f : 0.0f;                         \
    float sp = fmaxf(logit, 0.0f) + log1pf(expf(-fabsf(logit))); \
    s0 += sp - logit * tb;                                       \
    float pr = 1.0f / (1.0f + expf(-logit));                     \
    s1 += pr; s2 += pr * tb; s3 += tb;                           \
    atomicAdd(&hist[TV], 1);                                     \
    lp[c0 + (K)] = fg ? (c0 + (K)) : -1;                         \
  }
  ELEM(p0.x, p1.x, tv.x, 0)
  ELEM(p0.y, p1.y, tv.y, 1)
  ELEM(p0.z, p1.z, tv.z, 2)
  ELEM(p0.w, p1.w, tv.w, 3)
#undef ELEM
  __syncthreads();

#pragma unroll
  for (int k = 0; k < 4; ++k) {
    int c = (k << 8) + tid;
    if (lp[c] >= 0) {
      int r = c >> 5, q = c & 31;
      if (q < TS - 1 && lp[c + 1] >= 0)  uniteL(lp, c, c + 1);
      if (r < TS - 1 && lp[c + TS] >= 0) uniteL(lp, c, c + TS);
    }
  }
  __syncthreads();
#pragma unroll
  for (int k = 0; k < 4; ++k) {
    int c = (k << 8) + tid;
    int gi = gbase + ((c >> 5) << 9) + (c & 31);
    if (lp[c] >= 0) {
      int rr = findL(lp, c);
      P[gi] = gbase + ((rr >> 5) << 9) + (rr & 31);
    } else {
      P[gi] = -1;
    }
  }

  for (int o = 32; o > 0; o >>= 1) {
    s0 += __shfl_down(s0, o);
    s1 += __shfl_down(s1, o);
    s2 += __shfl_down(s2, o);
    s3 += __shfl_down(s3, o);
  }
  int lane = tid & 63, wid = tid >> 6;
  if (!lane) { red[wid][0] = s0; red[wid][1] = s1; red[wid][2] = s2; red[wid][3] = s3; }
  __syncthreads();
  double* row = part + (size_t)bid * NPART;
  if (tid <= TMAX) row[4 + tid] = (double)hist[tid];
  if (!tid) {
    row[0] = red[0][0] + red[1][0] + red[2][0] + red[3][0];
    row[1] = red[0][1] + red[1][1] + red[2][1] + red[3][1];
    row[2] = red[0][2] + red[1][2] + red[2][2] + red[3][2];
    row[3] = red[0][3] + red[1][3] + red[2][3] + red[3][3];
  }
}

// ---- k_border: seam unions + block0 scalar reduce ----
__global__ __launch_bounds__(256) void k_border(int* __restrict__ P,
                                                const double* __restrict__ part,
                                                Scalars* __restrict__ sc) {
  int tid = threadIdx.x;
  int bid = blockIdx.x;
  if (bid == 0) {
    int lane = tid & 63, wv = tid >> 6;
    double v[21];
#pragma unroll
    for (int j = 0; j < 21; ++j) v[j] = 0.0;
    for (int r = tid; r < NBLK; r += 256) {
      const double* row = part + (size_t)r * NPART;
#pragma unroll
      for (int j = 0; j < 21; ++j) v[j] += row[j];
    }
#pragma unroll
    for (int o = 32; o > 0; o >>= 1) {
#pragma unroll
      for (int j = 0; j < 21; ++j) v[j] += __shfl_down(v[j], o);
    }
    __shared__ double redr[4][21];
    if (!lane) {
#pragma unroll
      for (int j = 0; j < 21; ++j) redr[wv][j] = v[j];
    }
    __syncthreads();
    if (!tid) {
#pragma unroll
      for (int j = 0; j < 21; ++j) v[j] = redr[0][j] + redr[1][j] + redr[2][j] + redr[3][j];
      sc->sums[0] = v[0]; sc->sums[1] = v[1]; sc->sums[2] = v[2]; sc->sums[3] = v[3];
      for (int j = 0; j <= TMAX; ++j) sc->cnt_t[j] = (int)(v[4 + j] + 0.5);
    }
  }
  for (int e = bid * 256 + tid; e < NEDGES; e += BORDER_BLOCKS * 256) {
    int dir = e >= EDGES_PER_DIR;
    int e2 = dir ? e - EDGES_PER_DIR : e;
    int b = e2 / (SEAMS * HH);
    int r2 = e2 - b * (SEAMS * HH);
    int seam = r2 >> 9;
    int pos = r2 & 511;
    int i, j;
    if (!dir) {
      int w = (TS - 1) + (seam << 5);
      i = b * HWSZ + (pos << 9) + w;
      j = i + 1;
    } else {
      int h = (TS - 1) + (seam << 5);
      i = b * HWSZ + (h << 9) + pos;
      j = i + WW;
    }
    if (P[i] >= 0 && P[j] >= 0) unite(P, i, j);
  }
}

// ---- k_flatscan: flatten + decoupled-lookback prefix + dof + zero interD range.
// All 1024 blocks are co-resident (256 thr, low VGPR) -> no deadlock; each block
// publishes its aggregate BEFORE polling predecessors. Dense order = root order
// (deterministic). Poll guard converts any surprise into a wrong (visible) value
// rather than a hang. ----
__global__ __launch_bounds__(256) void k_flatscan(int* __restrict__ P,
                                                  unsigned* __restrict__ state,
                                                  int* __restrict__ dof,
                                                  int* __restrict__ interD,
                                                  Scalars* __restrict__ sc) {
  __shared__ int redi[4];
  __shared__ int redp[4];
  __shared__ int wtot[4];
  int tid = threadIdx.x;
  int bid = blockIdx.x;
  int lane = tid & 63, wv = tid >> 6;
  int i0 = (bid << 10) + (tid << 2);
  int4 pv = *(const int4*)(P + i0);
  int4 rv;
  rv.x = (pv.x < 0) ? -1 : chaseRO(P, pv.x);
  rv.y = (pv.y < 0) ? -1 : chaseRO(P, pv.y);
  rv.z = (pv.z < 0) ? -1 : chaseRO(P, pv.z);
  rv.w = (pv.w < 0) ? -1 : chaseRO(P, pv.w);
  *(int4*)(P + i0) = rv;        // owner-exclusive; root status immutable
  int isr[4] = { rv.x == i0 + 0, rv.y == i0 + 1, rv.z == i0 + 2, rv.w == i0 + 3 };
  int cme = isr[0] + isr[1] + isr[2] + isr[3];
  int c = cme;
  for (int o = 32; o > 0; o >>= 1) c += __shfl_down(c, o);
  if (!lane) redi[wv] = c;
  __syncthreads();
  int btot = redi[0] + redi[1] + redi[2] + redi[3];
  if (!tid) atomicExch(&state[bid], (unsigned)btot | FLAGBIT);  // publish

  // lookback: poll all predecessors' aggregates in parallel
  int pre = 0;
  for (int j = tid; j < bid; j += 256) {
    unsigned v;
    int guard = 0;
    do { v = atomicAdd(&state[j], 0u); } while (!(v & FLAGBIT) && ++guard < POLLCAP);
    pre += (int)(v & 0x7FFFFFFFu);
  }
  for (int o = 32; o > 0; o >>= 1) pre += __shfl_down(pre, o);
  if (!lane) redp[wv] = pre;
  __syncthreads();
  int PRE = redp[0] + redp[1] + redp[2] + redp[3];
  if (bid == NBLK - 1 && !tid) sc->n_comp = PRE + btot;

  // block-local exclusive scan of cme
  int v = cme;
  for (int o = 1; o < 64; o <<= 1) {
    int u = __shfl_up(v, o);
    if (lane >= o) v += u;
  }
  if (lane == 63) wtot[wv] = v;
  __syncthreads();
  int add = 0;
  for (int w = 0; w < wv; ++w) add += wtot[w];
  int d = PRE + v + add - cme;
#pragma unroll
  for (int k = 0; k < 4; ++k) {
    if (isr[k]) { dof[i0 + k] = d; ++d; }
  }
  // zero this block's interD dense range [PRE, PRE+btot)
  size_t zs = (size_t)PRE * RSTRIDE;
  size_t ze = (size_t)(PRE + btot) * RSTRIDE;
  size_t zcap = (size_t)CAP * RSTRIDE;
  if (ze > zcap) ze = zcap;
  for (size_t j = zs + tid; j < ze; j += 256) interD[j] = 0;
}

// ---- k_interall: confusion counts for ALL targets 0..16 (row sum = comp size) ----
__global__ __launch_bounds__(256) void k_interall(const int* __restrict__ P,
                                                  const int* __restrict__ tgt,
                                                  const int* __restrict__ dof,
                                                  int* __restrict__ interD) {
  int g = blockIdx.x * 256 + threadIdx.x;
  int i0 = g << 2;
  int4 rv = *(const int4*)(P + i0);
  int4 tv = *(const int4*)(tgt + i0);
#define DO(R, T)                                                     \
  if ((R) >= 0) {                                                    \
    int dd = dof[R];                                                 \
    if ((unsigned)dd < CAP) atomicAdd(&interD[(size_t)dd * RSTRIDE + (T)], 1); \
  }
  DO(rv.x, tv.x) DO(rv.y, tv.y) DO(rv.z, tv.z) DO(rv.w, tv.w)
#undef DO
}

// ---- k_scanmins: per-(block,t) min keys over 512 comps/block (2/thread) ----
__global__ __launch_bounds__(256) void k_scanmins(const Scalars* __restrict__ sc,
                                                  const int* __restrict__ interD,
                                                  unsigned long long* __restrict__ bm) {
  int tid = threadIdx.x;
  int n_comp = sc->n_comp;
  if (n_comp > CAP) n_comp = CAP;
  int d0 = (blockIdx.x << 9) + tid;
  int d1 = d0 + 256;
  int r0[RSTRIDE], r1[RSTRIDE];
  int cp0 = 0, cp1 = 0;
  if (d0 < n_comp) {
    const int4* rp = (const int4*)(interD + (size_t)d0 * RSTRIDE);
#pragma unroll
    for (int k = 0; k < 5; ++k) {
      int4 r4 = rp[k];
      r0[(k << 2) + 0] = r4.x; r0[(k << 2) + 1] = r4.y;
      r0[(k << 2) + 2] = r4.z; r0[(k << 2) + 3] = r4.w;
      cp0 += r4.x + r4.y + r4.z + r4.w;
    }
  }
  if (d1 < n_comp) {
    const int4* rp = (const int4*)(interD + (size_t)d1 * RSTRIDE);
#pragma unroll
    for (int k = 0; k < 5; ++k) {
      int4 r4 = rp[k];
      r1[(k << 2) + 0] = r4.x; r1[(k << 2) + 1] = r4.y;
      r1[(k << 2) + 2] = r4.z; r1[(k << 2) + 3] = r4.w;
      cp1 += r4.x + r4.y + r4.z + r4.w;
    }
  }
  __shared__ unsigned long long wmin[4][16];
  float cf0 = (float)cp0, cf1 = (float)cp1;
  int lane = tid & 63, wv = tid >> 6;
#pragma unroll
  for (int t = 1; t <= TMAX; ++t) {
    unsigned long long key = ~0ULL;
    float ctf = (float)sc->cnt_t[t];
    if (d0 < n_comp) {
      float loss = pair_loss(cf0, (float)r0[t], ctf);
      key = ((unsigned long long)__float_as_uint(loss) << 32) | (unsigned)d0;
    }
    if (d1 < n_comp) {
      float loss = pair_loss(cf1, (float)r1[t], ctf);
      unsigned long long k2 = ((unsigned long long)__float_as_uint(loss) << 32) | (unsigned)d1;
      if (k2 < key) key = k2;
    }
    for (int o = 32; o > 0; o >>= 1) {
      unsigned long long kk = __shfl_down(key, o);
      if (kk < key) key = kk;
    }
    if (!lane) wmin[wv][t - 1] = key;
  }
  __syncthreads();
  if (tid < 16) {
    unsigned long long m = wmin[0][tid];
    if (wmin[1][tid] < m) m = wmin[1][tid];
    if (wmin[2][tid] < m) m = wmin[2][tid];
    if (wmin[3][tid] < m) m = wmin[3][tid];
    bm[(size_t)tid * SMB + blockIdx.x] = m;
  }
}

// ---- k_greedy: 16 waves, redundant wave-synchronous greedy over LDS mins ----
__global__ __launch_bounds__(1024) void k_greedy(const Scalars* __restrict__ sc,
                                                 const int* __restrict__ interD,
                                                 const unsigned long long* __restrict__ bm,
                                                 float* __restrict__ out) {
  __shared__ unsigned long long lbm[16 * SMB];    // 32 KiB
  int tid = threadIdx.x;
  int lane = tid & 63;
#pragma unroll
  for (int k = 0; k < 4; ++k) lbm[tid + (k << 10)] = bm[tid + (k << 10)];
  __syncthreads();

  int n_comp = sc->n_comp;
  if (n_comp > CAP) n_comp = CAP;
  double acc = 0.0;
  int matched = 0, un = 0, nused = 0;
  int used_reg = -1;            // per-wave: lane u (u<nused) holds u-th used id

  for (int t = 1; t <= TMAX; ++t) {
    int ct = sc->cnt_t[t];
    if (ct == 0) continue;
    const int rowoff = (t - 1) * SMB;
    for (int iter = 0; iter < 40; ++iter) {
      // min over 256 LDS entries: 4 per lane, wave butterfly (redundant per wave)
      unsigned long long key = lbm[rowoff + lane];
#pragma unroll
      for (int k = 1; k < 4; ++k) {
        unsigned long long kk = lbm[rowoff + lane + (k << 6)];
        if (kk < key) key = kk;
      }
      for (int o = 32; o > 0; o >>= 1) {
        unsigned long long kk = __shfl_xor(key, o);
        if (kk < key) key = kk;
      }
      if (key == ~0ULL) { un += 1; break; }
      int dd = (int)(key & 0xFFFFFFFFu);
      bool ex = false;
      for (int u = 0; u < nused; ++u) {
        int uid = __shfl(used_reg, u);
        if (uid == dd) { ex = true; break; }
      }
      if (!ex) {
        acc += (double)__uint_as_float((unsigned)(key >> 32));
        matched += 1;
        if (lane == nused) used_reg = dd;
        nused += 1;
        break;
      }
      // retry: rebuild block b's min (512 comps, 8/lane), excluding used comps
      int b = dd >> 9;
      unsigned long long nk = ~0ULL;
#pragma unroll
      for (int k = 0; k < 8; ++k) {
        int d2 = (b << 9) + lane + (k << 6);
        if (d2 < n_comp) {
          bool ex2 = false;
          for (int u = 0; u < nused; ++u) {
            int uid = __shfl(used_reg, u);
            if (uid == d2) { ex2 = true; break; }
          }
          if (!ex2) {
            const int* rrow = interD + (size_t)d2 * RSTRIDE;
            int c = 0;
#pragma unroll
            for (int j = 0; j < RSTRIDE; ++j) c += rrow[j];
            float loss = pair_loss((float)c, (float)rrow[t], (float)ct);
            unsigned long long cand = ((unsigned long long)__float_as_uint(loss) << 32) | (unsigned)d2;
            if (cand < nk) nk = cand;
          }
        }
      }
      for (int o = 32; o > 0; o >>= 1) {
        unsigned long long kk = __shfl_xor(nk, o);
        if (kk < nk) nk = kk;
      }
      __syncthreads();            // all reads of row complete before rewrite
      if (!tid) lbm[rowoff + b] = nk;
      __syncthreads();            // write visible before next iteration
    }
  }

  if (!tid) {
    double Nd = (double)NPIX;
    double res = sc->sums[0] / Nd
               + 1.0 - (2.0 * sc->sums[2] + 1.0) / (sc->sums[1] + sc->sums[3] + 1.0);
    out[0] = (float)(res + acc + (double)(n_comp - matched) + (double)un);
  }
}

extern "C" void kernel_launch(void* const* d_in, const int* in_sizes, int n_in,
                              void* d_out, int out_size, void* d_ws, size_t ws_size,
                              hipStream_t stream) {
  (void)in_sizes; (void)n_in; (void)out_size; (void)ws_size;
  const float* pred = (const float*)d_in[0];
  const int* tgt = (const int*)d_in[1];
  float* out = (float*)d_out;

  char* w = (char*)d_ws;
  int* P     = (int*)w;            w += (size_t)NPIX * 4;     // parents -> roots
  int* dof   = (int*)w;            w += (size_t)NPIX * 4;     // dense id at roots
  double* part = (double*)w;       w += (size_t)NBLK * NPART * 8;
  Scalars* sc = (Scalars*)w;       w += 256;
  unsigned* state = (unsigned*)w;  w += 4096;                 // 1024 lookback slots
  unsigned long long* bm = (unsigned long long*)w; w += (size_t)16 * SMB * 8;
  int* interD = (int*)w;           // CAP * RSTRIDE * 4 = 10.5 MB

  k_tile<<<NBLK, 256, 0, stream>>>(pred, tgt, P, part, state);
  k_border<<<BORDER_BLOCKS, 256, 0, stream>>>(P, part, sc);
  k_flatscan<<<NBLK, 256, 0, stream>>>(P, state, dof, interD, sc);
  k_interall<<<NBLK, 256, 0, stream>>>(P, tgt, dof, interD);
  k_scanmins<<<SMB, 256, 0, stream>>>(sc, interD, bm);
  k_greedy<<<1, 1024, 0, stream>>>(sc, interD, bm, out);
}

// Round 12
// 124.354 us; speedup vs baseline: 1.0580x; 1.0580x over previous
//
#include <hip/hip_runtime.h>
#include <math.h>

#define HH 512
#define WW 512
#define HWSZ (HH * WW)          // 262144
#define NB 4
#define NPIX (NB * HWSZ)        // 1048576
#define TMAX 16

#define CAP 131072              // dense component capacity (observed n_comp ~70k)
#define NPART 24                // padded partials row (21 used)
#define NBLK 1024               // pixel-pass blocks (4 px/thread)
#define SMB 256                 // scanmins blocks; each covers 512 dense comps
#define RSTRIDE 20              // interD row stride in ints (80 B; 17 used)

// two-level CC: 32x32 tiles, 16 tiles/row, 256 tiles/img, 1024 blocks
#define TS 32
#define SEAMS 15
#define EDGES_PER_DIR (NB * SEAMS * HH)   // 30720
#define NEDGES (2 * EDGES_PER_DIR)        // 61440
#define BORDER_BLOCKS 64

struct Scalars {
  double sums[4];               // bce, sum_p, sum_pt, sum_t
  int cnt_t[TMAX + 1];
  int n_comp;
};

__device__ __forceinline__ float pair_loss(float cp, float it, float ctf) {
  const float Nf = (float)NPIX;
  float bce = (Nf * 0.69314718f + cp * 0.62011451f - it) / Nf;  // SP0, SP1-SP0
  float sum_pt = 0.5f * ctf + 0.23105858f * it;                 // S1-0.5
  float sum_p = 0.5f * Nf + 0.23105858f * cp;
  float dice = 1.0f - (2.0f * sum_pt + 1.0f) / (sum_p + ctf + 1.0f);
  return bce + dice;            // always > 0 -> float bits order == value order
}

// ---- union-find (max-root) with path-halving ----
__device__ __forceinline__ int chaseRO(const int* __restrict__ P, int x) {
  int p = P[x];
  while (p != x) { x = p; p = P[x]; }
  return x;
}
__device__ __forceinline__ int findRootH(int* P, int x) {
  int p = P[x];
  while (p != x) {
    int gp = P[p];
    if (gp == p) return p;
    P[x] = gp;
    x = gp; p = P[x];
  }
  return x;
}
__device__ void unite(int* P, int a, int b) {
  a = findRootH(P, a);
  b = findRootH(P, b);
  for (;;) {
    if (a == b) return;
    if (a > b) { int t = a; a = b; b = t; }
    int old = atomicMax(&P[a], b);
    if (old == a) return;
    a = findRootH(P, old);
    b = findRootH(P, b);
  }
}
__device__ __forceinline__ int findL(const int* lp, int x) {
  int p = lp[x];
  while (p != x) { x = p; p = lp[x]; }
  return x;
}
__device__ void uniteL(int* lp, int a, int b) {
  a = findL(lp, a);
  b = findL(lp, b);
  for (;;) {
    if (a == b) return;
    if (a > b) { int t = a; a = b; b = t; }
    int old = atomicMax(&lp[a], b);
    if (old == a) return;
    a = findL(lp, old);
    b = findL(lp, b);
  }
}

// ---- k_tile: fused init + per-tile 32x32 LDS CC ----
__global__ __launch_bounds__(256) void k_tile(const float* __restrict__ pred,
                                              const int* __restrict__ tgt,
                                              int* __restrict__ P,
                                              double* __restrict__ part) {
  __shared__ int lp[TS * TS];
  __shared__ int hist[TMAX + 1];
  __shared__ double red[4][4];
  int tid = threadIdx.x, bid = blockIdx.x;
  if (tid <= TMAX) hist[tid] = 0;
  int b = bid >> 8;
  int ty = (bid >> 4) & 15, tx = bid & 15;
  int gbase = b * HWSZ + ((ty << 5) << 9) + (tx << 5);
  int c0 = tid << 2;                  // 4 consecutive pixels, same tile row
  int hw0 = (gbase - b * HWSZ) + ((c0 >> 5) << 9) + (c0 & 31);
  int gi0 = b * HWSZ + hw0;
  const float* pb = pred + ((size_t)(b << 1)) * HWSZ;
  float4 p0 = *(const float4*)(pb + hw0);
  float4 p1 = *(const float4*)(pb + HWSZ + hw0);
  int4 tv = *(const int4*)(tgt + gi0);
  __syncthreads();                     // hist zero visible

  float s0 = 0.f, s1 = 0.f, s2 = 0.f, s3 = 0.f;
#define ELEM(P0, P1, TV, K)                                      \
  {                                                              \
    bool fg = (P1) > (P0);                                       \
    float logit = fg ? (P1) : 0.0f;                              \
    float tb = ((TV) > 0) ? 1.0f : 0.0f;                         \
    float sp = fmaxf(logit, 0.0f) + log1pf(expf(-fabsf(logit))); \
    s0 += sp - logit * tb;                                       \
    float pr = 1.0f / (1.0f + expf(-logit));                     \
    s1 += pr; s2 += pr * tb; s3 += tb;                           \
    atomicAdd(&hist[TV], 1);                                     \
    lp[c0 + (K)] = fg ? (c0 + (K)) : -1;                         \
  }
  ELEM(p0.x, p1.x, tv.x, 0)
  ELEM(p0.y, p1.y, tv.y, 1)
  ELEM(p0.z, p1.z, tv.z, 2)
  ELEM(p0.w, p1.w, tv.w, 3)
#undef ELEM
  __syncthreads();

#pragma unroll
  for (int k = 0; k < 4; ++k) {
    int c = (k << 8) + tid;
    if (lp[c] >= 0) {
      int r = c >> 5, q = c & 31;
      if (q < TS - 1 && lp[c + 1] >= 0)  uniteL(lp, c, c + 1);
      if (r < TS - 1 && lp[c + TS] >= 0) uniteL(lp, c, c + TS);
    }
  }
  __syncthreads();
#pragma unroll
  for (int k = 0; k < 4; ++k) {
    int c = (k << 8) + tid;
    int gi = gbase + ((c >> 5) << 9) + (c & 31);
    if (lp[c] >= 0) {
      int rr = findL(lp, c);
      P[gi] = gbase + ((rr >> 5) << 9) + (rr & 31);
    } else {
      P[gi] = -1;
    }
  }

  for (int o = 32; o > 0; o >>= 1) {
    s0 += __shfl_down(s0, o);
    s1 += __shfl_down(s1, o);
    s2 += __shfl_down(s2, o);
    s3 += __shfl_down(s3, o);
  }
  int lane = tid & 63, wid = tid >> 6;
  if (!lane) { red[wid][0] = s0; red[wid][1] = s1; red[wid][2] = s2; red[wid][3] = s3; }
  __syncthreads();
  double* row = part + (size_t)bid * NPART;
  if (tid <= TMAX) row[4 + tid] = (double)hist[tid];
  if (!tid) {
    row[0] = red[0][0] + red[1][0] + red[2][0] + red[3][0];
    row[1] = red[0][1] + red[1][1] + red[2][1] + red[3][1];
    row[2] = red[0][2] + red[1][2] + red[2][2] + red[3][2];
    row[3] = red[0][3] + red[1][3] + red[2][3] + red[3][3];
  }
}

// ---- k_border: seam unions + block0 scalar reduce ----
__global__ __launch_bounds__(256) void k_border(int* __restrict__ P,
                                                const double* __restrict__ part,
                                                Scalars* __restrict__ sc) {
  int tid = threadIdx.x;
  int bid = blockIdx.x;
  if (bid == 0) {
    int lane = tid & 63, wv = tid >> 6;
    double v[21];
#pragma unroll
    for (int j = 0; j < 21; ++j) v[j] = 0.0;
    for (int r = tid; r < NBLK; r += 256) {
      const double* row = part + (size_t)r * NPART;
#pragma unroll
      for (int j = 0; j < 21; ++j) v[j] += row[j];
    }
#pragma unroll
    for (int o = 32; o > 0; o >>= 1) {
#pragma unroll
      for (int j = 0; j < 21; ++j) v[j] += __shfl_down(v[j], o);
    }
    __shared__ double redr[4][21];
    if (!lane) {
#pragma unroll
      for (int j = 0; j < 21; ++j) redr[wv][j] = v[j];
    }
    __syncthreads();
    if (!tid) {
#pragma unroll
      for (int j = 0; j < 21; ++j) v[j] = redr[0][j] + redr[1][j] + redr[2][j] + redr[3][j];
      sc->sums[0] = v[0]; sc->sums[1] = v[1]; sc->sums[2] = v[2]; sc->sums[3] = v[3];
      for (int j = 0; j <= TMAX; ++j) sc->cnt_t[j] = (int)(v[4 + j] + 0.5);
    }
  }
  for (int e = bid * 256 + tid; e < NEDGES; e += BORDER_BLOCKS * 256) {
    int dir = e >= EDGES_PER_DIR;
    int e2 = dir ? e - EDGES_PER_DIR : e;
    int b = e2 / (SEAMS * HH);
    int r2 = e2 - b * (SEAMS * HH);
    int seam = r2 >> 9;
    int pos = r2 & 511;
    int i, j;
    if (!dir) {
      int w = (TS - 1) + (seam << 5);
      i = b * HWSZ + (pos << 9) + w;
      j = i + 1;
    } else {
      int h = (TS - 1) + (seam << 5);
      i = b * HWSZ + (h << 9) + pos;
      j = i + WW;
    }
    if (P[i] >= 0 && P[j] >= 0) unite(P, i, j);
  }
}

// ---- k_flatb: in-place flatten + per-block root counts (fused bcnt) ----
__global__ __launch_bounds__(256) void k_flatb(int* __restrict__ P,
                                               int* __restrict__ bcnt) {
  __shared__ int redi[4];
  int tid = threadIdx.x;
  int g = blockIdx.x * 256 + tid;
  int i0 = g << 2;
  int4 pv = *(const int4*)(P + i0);
  int4 rv;
  rv.x = (pv.x < 0) ? -1 : chaseRO(P, pv.x);
  rv.y = (pv.y < 0) ? -1 : chaseRO(P, pv.y);
  rv.z = (pv.z < 0) ? -1 : chaseRO(P, pv.z);
  rv.w = (pv.w < 0) ? -1 : chaseRO(P, pv.w);
  *(int4*)(P + i0) = rv;        // owner-exclusive store; root status immutable
  int c = (rv.x == i0 + 0) + (rv.y == i0 + 1) + (rv.z == i0 + 2) + (rv.w == i0 + 3);
  for (int o = 32; o > 0; o >>= 1) c += __shfl_down(c, o);
  int lane = tid & 63, wv = tid >> 6;
  if (!lane) redi[wv] = c;
  __syncthreads();
  if (!tid) bcnt[blockIdx.x] = redi[0] + redi[1] + redi[2] + redi[3];
}

// ---- k_scatter: global prefix + dense ids at roots + zero own interD range ----
__global__ __launch_bounds__(256) void k_scatter(const int* __restrict__ P,
                                                 const int* __restrict__ bcnt,
                                                 int* __restrict__ dof,
                                                 int* __restrict__ interD,
                                                 Scalars* __restrict__ sc) {
  __shared__ int redi[4];
  __shared__ int redp4[4];
  __shared__ int wtot[4];
  int tid = threadIdx.x;
  int bid = blockIdx.x;
  int lane = tid & 63, wv = tid >> 6;
  int i0 = (bid << 10) + (tid << 2);
  int4 rv = *(const int4*)(P + i0);
  int isr[4] = { rv.x == i0 + 0, rv.y == i0 + 1, rv.z == i0 + 2, rv.w == i0 + 3 };
  int cme = isr[0] + isr[1] + isr[2] + isr[3];
  // global prefix over bcnt
  int4 bv = *(const int4*)(bcnt + (tid << 2));
  int j0 = tid << 2;
  int tot = bv.x + bv.y + bv.z + bv.w;
  int pre = ((j0 + 0 < bid) ? bv.x : 0) + ((j0 + 1 < bid) ? bv.y : 0)
          + ((j0 + 2 < bid) ? bv.z : 0) + ((j0 + 3 < bid) ? bv.w : 0);
  for (int o = 32; o > 0; o >>= 1) {
    tot += __shfl_down(tot, o);
    pre += __shfl_down(pre, o);
  }
  if (!lane) { redi[wv] = tot; redp4[wv] = pre; }
  __syncthreads();
  tot = redi[0] + redi[1] + redi[2] + redi[3];
  pre = redp4[0] + redp4[1] + redp4[2] + redp4[3];
  if (bid == 0 && tid == 0) sc->n_comp = tot;
  // block-local exclusive scan of cme
  int v = cme;
  for (int o = 1; o < 64; o <<= 1) {
    int u = __shfl_up(v, o);
    if (lane >= o) v += u;
  }
  if (lane == 63) wtot[wv] = v;
  __syncthreads();
  int add = 0;
  for (int w = 0; w < wv; ++w) add += wtot[w];
  int d = pre + v + add - cme;
#pragma unroll
  for (int k = 0; k < 4; ++k) {
    if (isr[k]) { dof[i0 + k] = d; ++d; }
  }
  // zero this block's interD dense range [pre, pre+btot)
  int btot = wtot[0] + wtot[1] + wtot[2] + wtot[3];
  size_t zs = (size_t)pre * RSTRIDE;
  size_t ze = (size_t)(pre + btot) * RSTRIDE;
  size_t zcap = (size_t)CAP * RSTRIDE;
  if (ze > zcap) ze = zcap;
  for (size_t j = zs + tid; j < ze; j += 256) interD[j] = 0;
}

// ---- k_interall: confusion counts for ALL targets 0..16 (row sum = comp size) ----
__global__ __launch_bounds__(256) void k_interall(const int* __restrict__ P,
                                                  const int* __restrict__ tgt,
                                                  const int* __restrict__ dof,
                                                  int* __restrict__ interD) {
  int g = blockIdx.x * 256 + threadIdx.x;
  int i0 = g << 2;
  int4 rv = *(const int4*)(P + i0);
  int4 tv = *(const int4*)(tgt + i0);
#define DO(R, T)                                                     \
  if ((R) >= 0) {                                                    \
    int dd = dof[R];                                                 \
    if ((unsigned)dd < CAP) atomicAdd(&interD[(size_t)dd * RSTRIDE + (T)], 1); \
  }
  DO(rv.x, tv.x) DO(rv.y, tv.y) DO(rv.z, tv.z) DO(rv.w, tv.w)
#undef DO
}

// ---- k_scanmins: per-(block,t) min keys over 512 comps/block (2/thread) ----
__global__ __launch_bounds__(256) void k_scanmins(const Scalars* __restrict__ sc,
                                                  const int* __restrict__ interD,
                                                  unsigned long long* __restrict__ bm) {
  int tid = threadIdx.x;
  int n_comp = sc->n_comp;
  if (n_comp > CAP) n_comp = CAP;
  int d0 = (blockIdx.x << 9) + tid;
  int d1 = d0 + 256;
  int r0[RSTRIDE], r1[RSTRIDE];
  int cp0 = 0, cp1 = 0;
  if (d0 < n_comp) {
    const int4* rp = (const int4*)(interD + (size_t)d0 * RSTRIDE);
#pragma unroll
    for (int k = 0; k < 5; ++k) {
      int4 r4 = rp[k];
      r0[(k << 2) + 0] = r4.x; r0[(k << 2) + 1] = r4.y;
      r0[(k << 2) + 2] = r4.z; r0[(k << 2) + 3] = r4.w;
      cp0 += r4.x + r4.y + r4.z + r4.w;
    }
  }
  if (d1 < n_comp) {
    const int4* rp = (const int4*)(interD + (size_t)d1 * RSTRIDE);
#pragma unroll
    for (int k = 0; k < 5; ++k) {
      int4 r4 = rp[k];
      r1[(k << 2) + 0] = r4.x; r1[(k << 2) + 1] = r4.y;
      r1[(k << 2) + 2] = r4.z; r1[(k << 2) + 3] = r4.w;
      cp1 += r4.x + r4.y + r4.z + r4.w;
    }
  }
  __shared__ unsigned long long wmin[4][16];
  float cf0 = (float)cp0, cf1 = (float)cp1;
  int lane = tid & 63, wv = tid >> 6;
#pragma unroll
  for (int t = 1; t <= TMAX; ++t) {
    unsigned long long key = ~0ULL;
    float ctf = (float)sc->cnt_t[t];
    if (d0 < n_comp) {
      float loss = pair_loss(cf0, (float)r0[t], ctf);
      key = ((unsigned long long)__float_as_uint(loss) << 32) | (unsigned)d0;
    }
    if (d1 < n_comp) {
      float loss = pair_loss(cf1, (float)r1[t], ctf);
      unsigned long long k2 = ((unsigned long long)__float_as_uint(loss) << 32) | (unsigned)d1;
      if (k2 < key) key = k2;
    }
    for (int o = 32; o > 0; o >>= 1) {
      unsigned long long kk = __shfl_down(key, o);
      if (kk < key) key = kk;
    }
    if (!lane) wmin[wv][t - 1] = key;
  }
  __syncthreads();
  if (tid < 16) {
    unsigned long long m = wmin[0][tid];
    if (wmin[1][tid] < m) m = wmin[1][tid];
    if (wmin[2][tid] < m) m = wmin[2][tid];
    if (wmin[3][tid] < m) m = wmin[3][tid];
    bm[(size_t)tid * SMB + blockIdx.x] = m;
  }
}

// ---- k_greedy: 16 waves, redundant wave-synchronous greedy over LDS mins ----
__global__ __launch_bounds__(1024) void k_greedy(const Scalars* __restrict__ sc,
                                                 const int* __restrict__ interD,
                                                 const unsigned long long* __restrict__ bm,
                                                 float* __restrict__ out) {
  __shared__ unsigned long long lbm[16 * SMB];    // 32 KiB
  int tid = threadIdx.x;
  int lane = tid & 63;
#pragma unroll
  for (int k = 0; k < 4; ++k) lbm[tid + (k << 10)] = bm[tid + (k << 10)];
  __syncthreads();

  int n_comp = sc->n_comp;
  if (n_comp > CAP) n_comp = CAP;
  double acc = 0.0;
  int matched = 0, un = 0, nused = 0;
  int used_reg = -1;            // per-wave: lane u (u<nused) holds u-th used id

  for (int t = 1; t <= TMAX; ++t) {
    int ct = sc->cnt_t[t];
    if (ct == 0) continue;
    const int rowoff = (t - 1) * SMB;
    for (int iter = 0; iter < 40; ++iter) {
      // min over 256 LDS entries: 4 per lane, wave butterfly (redundant per wave)
      unsigned long long key = lbm[rowoff + lane];
#pragma unroll
      for (int k = 1; k < 4; ++k) {
        unsigned long long kk = lbm[rowoff + lane + (k << 6)];
        if (kk < key) key = kk;
      }
      for (int o = 32; o > 0; o >>= 1) {
        unsigned long long kk = __shfl_xor(key, o);
        if (kk < key) key = kk;
      }
      if (key == ~0ULL) { un += 1; break; }
      int dd = (int)(key & 0xFFFFFFFFu);
      bool ex = false;
      for (int u = 0; u < nused; ++u) {
        int uid = __shfl(used_reg, u);
        if (uid == dd) { ex = true; break; }
      }
      if (!ex) {
        acc += (double)__uint_as_float((unsigned)(key >> 32));
        matched += 1;
        if (lane == nused) used_reg = dd;
        nused += 1;
        break;
      }
      // retry: rebuild block b's min (512 comps, 8/lane), excluding used comps
      int b = dd >> 9;
      unsigned long long nk = ~0ULL;
#pragma unroll
      for (int k = 0; k < 8; ++k) {
        int d2 = (b << 9) + lane + (k << 6);
        if (d2 < n_comp) {
          bool ex2 = false;
          for (int u = 0; u < nused; ++u) {
            int uid = __shfl(used_reg, u);
            if (uid == d2) { ex2 = true; break; }
          }
          if (!ex2) {
            const int* rrow = interD + (size_t)d2 * RSTRIDE;
            int c = 0;
#pragma unroll
            for (int j = 0; j < RSTRIDE; ++j) c += rrow[j];
            float loss = pair_loss((float)c, (float)rrow[t], (float)ct);
            unsigned long long cand = ((unsigned long long)__float_as_uint(loss) << 32) | (unsigned)d2;
            if (cand < nk) nk = cand;
          }
        }
      }
      for (int o = 32; o > 0; o >>= 1) {
        unsigned long long kk = __shfl_xor(nk, o);
        if (kk < nk) nk = kk;
      }
      __syncthreads();            // all reads of row complete before rewrite
      if (!tid) lbm[rowoff + b] = nk;
      __syncthreads();            // write visible before next iteration
    }
  }

  if (!tid) {
    double Nd = (double)NPIX;
    double res = sc->sums[0] / Nd
               + 1.0 - (2.0 * sc->sums[2] + 1.0) / (sc->sums[1] + sc->sums[3] + 1.0);
    out[0] = (float)(res + acc + (double)(n_comp - matched) + (double)un);
  }
}

extern "C" void kernel_launch(void* const* d_in, const int* in_sizes, int n_in,
                              void* d_out, int out_size, void* d_ws, size_t ws_size,
                              hipStream_t stream) {
  (void)in_sizes; (void)n_in; (void)out_size; (void)ws_size;
  const float* pred = (const float*)d_in[0];
  const int* tgt = (const int*)d_in[1];
  float* out = (float*)d_out;

  char* w = (char*)d_ws;
  int* P     = (int*)w;            w += (size_t)NPIX * 4;     // parents -> roots
  int* dof   = (int*)w;            w += (size_t)NPIX * 4;     // dense id at roots
  double* part = (double*)w;       w += (size_t)NBLK * NPART * 8;
  Scalars* sc = (Scalars*)w;       w += 256;
  int* bcnt  = (int*)w;            w += 4096;                 // 1024 ints
  unsigned long long* bm = (unsigned long long*)w; w += (size_t)16 * SMB * 8;
  int* interD = (int*)w;           // CAP * RSTRIDE * 4 = 10.5 MB

  k_tile<<<NBLK, 256, 0, stream>>>(pred, tgt, P, part);
  k_border<<<BORDER_BLOCKS, 256, 0, stream>>>(P, part, sc);
  k_flatb<<<NBLK, 256, 0, stream>>>(P, bcnt);
  k_scatter<<<NBLK, 256, 0, stream>>>(P, bcnt, dof, interD, sc);
  k_interall<<<NBLK, 256, 0, stream>>>(P, tgt, dof, interD);
  k_scanmins<<<SMB, 256, 0, stream>>>(sc, interD, bm);
  k_greedy<<<1, 1024, 0, stream>>>(sc, interD, bm, out);
}

// Round 13
// 123.039 us; speedup vs baseline: 1.0693x; 1.0107x over previous
//
#include <hip/hip_runtime.h>
#include <math.h>

#define HH 512
#define WW 512
#define HWSZ (HH * WW)          // 262144
#define NB 4
#define NPIX (NB * HWSZ)        // 1048576
#define TMAX 16

#define CAP 131072              // dense component capacity (observed n_comp ~70k)
#define NPART 24                // padded partials row (21 used)
#define NBLK 1024               // pixel-pass blocks (4 px/thread)
#define SMB 256                 // scanmins blocks; each covers 512 dense comps
#define RSTRIDE 20              // interD row stride in ints (80 B; 17 used)
#define ZCHUNK ((CAP * RSTRIDE) / NBLK)   // 2560 ints zeroed per k_tile block

// two-level CC: 32x32 tiles, 16 tiles/row, 256 tiles/img, 1024 blocks
#define TS 32
#define SEAMS 15
#define EDGES_PER_DIR (NB * SEAMS * HH)   // 30720
#define NEDGES (2 * EDGES_PER_DIR)        // 61440
#define BORDER_BLOCKS 64

struct Scalars {
  double sums[4];               // bce, sum_p, sum_pt, sum_t
  int cnt_t[TMAX + 1];
  int n_comp;
};

__device__ __forceinline__ float pair_loss(float cp, float it, float ctf) {
  const float Nf = (float)NPIX;
  float bce = (Nf * 0.69314718f + cp * 0.62011451f - it) / Nf;  // SP0, SP1-SP0
  float sum_pt = 0.5f * ctf + 0.23105858f * it;                 // S1-0.5
  float sum_p = 0.5f * Nf + 0.23105858f * cp;
  float dice = 1.0f - (2.0f * sum_pt + 1.0f) / (sum_p + ctf + 1.0f);
  return bce + dice;            // always > 0 -> float bits order == value order
}

// ---- union-find (max-root) with path-halving ----
__device__ __forceinline__ int chaseRO(const int* __restrict__ P, int x) {
  int p = P[x];
  while (p != x) { x = p; p = P[x]; }
  return x;
}
__device__ __forceinline__ int findRootH(int* P, int x) {
  int p = P[x];
  while (p != x) {
    int gp = P[p];
    if (gp == p) return p;
    P[x] = gp;
    x = gp; p = P[x];
  }
  return x;
}
__device__ void unite(int* P, int a, int b) {
  a = findRootH(P, a);
  b = findRootH(P, b);
  for (;;) {
    if (a == b) return;
    if (a > b) { int t = a; a = b; b = t; }
    int old = atomicMax(&P[a], b);
    if (old == a) return;
    a = findRootH(P, old);
    b = findRootH(P, b);
  }
}
__device__ __forceinline__ int findL(const int* lp, int x) {
  int p = lp[x];
  while (p != x) { x = p; p = lp[x]; }
  return x;
}
__device__ void uniteL(int* lp, int a, int b) {
  a = findL(lp, a);
  b = findL(lp, b);
  for (;;) {
    if (a == b) return;
    if (a > b) { int t = a; a = b; b = t; }
    int old = atomicMax(&lp[a], b);
    if (old == a) return;
    a = findL(lp, old);
    b = findL(lp, b);
  }
}

// ---- k_tile: fused init + per-tile 32x32 LDS CC + blanket interD zero ----
__global__ __launch_bounds__(256) void k_tile(const float* __restrict__ pred,
                                              const int* __restrict__ tgt,
                                              int* __restrict__ P,
                                              double* __restrict__ part,
                                              int* __restrict__ interD) {
  __shared__ int lp[TS * TS];
  __shared__ int hist[TMAX + 1];
  __shared__ double red[4][4];
  int tid = threadIdx.x, bid = blockIdx.x;
  if (tid <= TMAX) hist[tid] = 0;
  int b = bid >> 8;
  int ty = (bid >> 4) & 15, tx = bid & 15;
  int gbase = b * HWSZ + ((ty << 5) << 9) + (tx << 5);
  int c0 = tid << 2;                  // 4 consecutive pixels, same tile row
  int hw0 = (gbase - b * HWSZ) + ((c0 >> 5) << 9) + (c0 & 31);
  int gi0 = b * HWSZ + hw0;
  const float* pb = pred + ((size_t)(b << 1)) * HWSZ;
  float4 p0 = *(const float4*)(pb + hw0);
  float4 p1 = *(const float4*)(pb + HWSZ + hw0);
  int4 tv = *(const int4*)(tgt + gi0);
  // blanket-zero this block's interD chunk (overlaps with CC compute below;
  // k_interall runs 3 dispatches later so ordering is safe)
  {
    int4* zb = (int4*)(interD + (size_t)bid * ZCHUNK);
    for (int j = tid; j < ZCHUNK / 4; j += 256) zb[j] = make_int4(0, 0, 0, 0);
  }
  __syncthreads();                     // hist zero visible

  float s0 = 0.f, s1 = 0.f, s2 = 0.f, s3 = 0.f;
#define ELEM(P0, P1, TV, K)                                      \
  {                                                              \
    bool fg = (P1) > (P0);                                       \
    float logit = fg ? (P1) : 0.0f;                              \
    float tb = ((TV) > 0) ? 1.0f : 0.0f;                         \
    float sp = fmaxf(logit, 0.0f) + log1pf(expf(-fabsf(logit))); \
    s0 += sp - logit * tb;                                       \
    float pr = 1.0f / (1.0f + expf(-logit));                     \
    s1 += pr; s2 += pr * tb; s3 += tb;                           \
    atomicAdd(&hist[TV], 1);                                     \
    lp[c0 + (K)] = fg ? (c0 + (K)) : -1;                         \
  }
  ELEM(p0.x, p1.x, tv.x, 0)
  ELEM(p0.y, p1.y, tv.y, 1)
  ELEM(p0.z, p1.z, tv.z, 2)
  ELEM(p0.w, p1.w, tv.w, 3)
#undef ELEM
  __syncthreads();

#pragma unroll
  for (int k = 0; k < 4; ++k) {
    int c = (k << 8) + tid;
    if (lp[c] >= 0) {
      int r = c >> 5, q = c & 31;
      if (q < TS - 1 && lp[c + 1] >= 0)  uniteL(lp, c, c + 1);
      if (r < TS - 1 && lp[c + TS] >= 0) uniteL(lp, c, c + TS);
    }
  }
  __syncthreads();
#pragma unroll
  for (int k = 0; k < 4; ++k) {
    int c = (k << 8) + tid;
    int gi = gbase + ((c >> 5) << 9) + (c & 31);
    if (lp[c] >= 0) {
      int rr = findL(lp, c);
      P[gi] = gbase + ((rr >> 5) << 9) + (rr & 31);
    } else {
      P[gi] = -1;
    }
  }

  for (int o = 32; o > 0; o >>= 1) {
    s0 += __shfl_down(s0, o);
    s1 += __shfl_down(s1, o);
    s2 += __shfl_down(s2, o);
    s3 += __shfl_down(s3, o);
  }
  int lane = tid & 63, wid = tid >> 6;
  if (!lane) { red[wid][0] = s0; red[wid][1] = s1; red[wid][2] = s2; red[wid][3] = s3; }
  __syncthreads();
  double* row = part + (size_t)bid * NPART;
  if (tid <= TMAX) row[4 + tid] = (double)hist[tid];
  if (!tid) {
    row[0] = red[0][0] + red[1][0] + red[2][0] + red[3][0];
    row[1] = red[0][1] + red[1][1] + red[2][1] + red[3][1];
    row[2] = red[0][2] + red[1][2] + red[2][2] + red[3][2];
    row[3] = red[0][3] + red[1][3] + red[2][3] + red[3][3];
  }
}

// ---- k_border: seam unions + block0 scalar reduce ----
__global__ __launch_bounds__(256) void k_border(int* __restrict__ P,
                                                const double* __restrict__ part,
                                                Scalars* __restrict__ sc) {
  int tid = threadIdx.x;
  int bid = blockIdx.x;
  if (bid == 0) {
    int lane = tid & 63, wv = tid >> 6;
    double v[21];
#pragma unroll
    for (int j = 0; j < 21; ++j) v[j] = 0.0;
    for (int r = tid; r < NBLK; r += 256) {
      const double* row = part + (size_t)r * NPART;
#pragma unroll
      for (int j = 0; j < 21; ++j) v[j] += row[j];
    }
#pragma unroll
    for (int o = 32; o > 0; o >>= 1) {
#pragma unroll
      for (int j = 0; j < 21; ++j) v[j] += __shfl_down(v[j], o);
    }
    __shared__ double redr[4][21];
    if (!lane) {
#pragma unroll
      for (int j = 0; j < 21; ++j) redr[wv][j] = v[j];
    }
    __syncthreads();
    if (!tid) {
#pragma unroll
      for (int j = 0; j < 21; ++j) v[j] = redr[0][j] + redr[1][j] + redr[2][j] + redr[3][j];
      sc->sums[0] = v[0]; sc->sums[1] = v[1]; sc->sums[2] = v[2]; sc->sums[3] = v[3];
      for (int j = 0; j <= TMAX; ++j) sc->cnt_t[j] = (int)(v[4 + j] + 0.5);
    }
  }
  for (int e = bid * 256 + tid; e < NEDGES; e += BORDER_BLOCKS * 256) {
    int dir = e >= EDGES_PER_DIR;
    int e2 = dir ? e - EDGES_PER_DIR : e;
    int b = e2 / (SEAMS * HH);
    int r2 = e2 - b * (SEAMS * HH);
    int seam = r2 >> 9;
    int pos = r2 & 511;
    int i, j;
    if (!dir) {
      int w = (TS - 1) + (seam << 5);
      i = b * HWSZ + (pos << 9) + w;
      j = i + 1;
    } else {
      int h = (TS - 1) + (seam << 5);
      i = b * HWSZ + (h << 9) + pos;
      j = i + WW;
    }
    if (P[i] >= 0 && P[j] >= 0) unite(P, i, j);
  }
}

// ---- k_flatb: in-place flatten + per-block root counts (fused bcnt) ----
__global__ __launch_bounds__(256) void k_flatb(int* __restrict__ P,
                                               int* __restrict__ bcnt) {
  __shared__ int redi[4];
  int tid = threadIdx.x;
  int g = blockIdx.x * 256 + tid;
  int i0 = g << 2;
  int4 pv = *(const int4*)(P + i0);
  int4 rv;
  rv.x = (pv.x < 0) ? -1 : chaseRO(P, pv.x);
  rv.y = (pv.y < 0) ? -1 : chaseRO(P, pv.y);
  rv.z = (pv.z < 0) ? -1 : chaseRO(P, pv.z);
  rv.w = (pv.w < 0) ? -1 : chaseRO(P, pv.w);
  *(int4*)(P + i0) = rv;        // owner-exclusive store; root status immutable
  int c = (rv.x == i0 + 0) + (rv.y == i0 + 1) + (rv.z == i0 + 2) + (rv.w == i0 + 3);
  for (int o = 32; o > 0; o >>= 1) c += __shfl_down(c, o);
  int lane = tid & 63, wv = tid >> 6;
  if (!lane) redi[wv] = c;
  __syncthreads();
  if (!tid) bcnt[blockIdx.x] = redi[0] + redi[1] + redi[2] + redi[3];
}

// ---- k_scatter: global prefix + dense ids at roots ----
__global__ __launch_bounds__(256) void k_scatter(const int* __restrict__ P,
                                                 const int* __restrict__ bcnt,
                                                 int* __restrict__ dof,
                                                 Scalars* __restrict__ sc) {
  __shared__ int redi[4];
  __shared__ int redp4[4];
  __shared__ int wtot[4];
  int tid = threadIdx.x;
  int bid = blockIdx.x;
  int lane = tid & 63, wv = tid >> 6;
  int i0 = (bid << 10) + (tid << 2);
  int4 rv = *(const int4*)(P + i0);
  int isr[4] = { rv.x == i0 + 0, rv.y == i0 + 1, rv.z == i0 + 2, rv.w == i0 + 3 };
  int cme = isr[0] + isr[1] + isr[2] + isr[3];
  // global prefix over bcnt
  int4 bv = *(const int4*)(bcnt + (tid << 2));
  int j0 = tid << 2;
  int tot = bv.x + bv.y + bv.z + bv.w;
  int pre = ((j0 + 0 < bid) ? bv.x : 0) + ((j0 + 1 < bid) ? bv.y : 0)
          + ((j0 + 2 < bid) ? bv.z : 0) + ((j0 + 3 < bid) ? bv.w : 0);
  for (int o = 32; o > 0; o >>= 1) {
    tot += __shfl_down(tot, o);
    pre += __shfl_down(pre, o);
  }
  if (!lane) { redi[wv] = tot; redp4[wv] = pre; }
  __syncthreads();
  tot = redi[0] + redi[1] + redi[2] + redi[3];
  pre = redp4[0] + redp4[1] + redp4[2] + redp4[3];
  if (bid == 0 && tid == 0) sc->n_comp = tot;
  // block-local exclusive scan of cme
  int v = cme;
  for (int o = 1; o < 64; o <<= 1) {
    int u = __shfl_up(v, o);
    if (lane >= o) v += u;
  }
  if (lane == 63) wtot[wv] = v;
  __syncthreads();
  int add = 0;
  for (int w = 0; w < wv; ++w) add += wtot[w];
  int d = pre + v + add - cme;
#pragma unroll
  for (int k = 0; k < 4; ++k) {
    if (isr[k]) { dof[i0 + k] = d; ++d; }
  }
}

// ---- k_interall: confusion counts for ALL targets 0..16 (row sum = comp size) ----
__global__ __launch_bounds__(256) void k_interall(const int* __restrict__ P,
                                                  const int* __restrict__ tgt,
                                                  const int* __restrict__ dof,
                                                  int* __restrict__ interD) {
  int g = blockIdx.x * 256 + threadIdx.x;
  int i0 = g << 2;
  int4 rv = *(const int4*)(P + i0);
  int4 tv = *(const int4*)(tgt + i0);
#define DO(R, T)                                                     \
  if ((R) >= 0) {                                                    \
    int dd = dof[R];                                                 \
    if ((unsigned)dd < CAP) atomicAdd(&interD[(size_t)dd * RSTRIDE + (T)], 1); \
  }
  DO(rv.x, tv.x) DO(rv.y, tv.y) DO(rv.z, tv.z) DO(rv.w, tv.w)
#undef DO
}

// ---- k_scanmins: per-(block,t) min keys over 512 comps/block (2/thread) ----
__global__ __launch_bounds__(256) void k_scanmins(const Scalars* __restrict__ sc,
                                                  const int* __restrict__ interD,
                                                  unsigned long long* __restrict__ bm) {
  int tid = threadIdx.x;
  int n_comp = sc->n_comp;
  if (n_comp > CAP) n_comp = CAP;
  int d0 = (blockIdx.x << 9) + tid;
  int d1 = d0 + 256;
  int r0[RSTRIDE], r1[RSTRIDE];
  int cp0 = 0, cp1 = 0;
  if (d0 < n_comp) {
    const int4* rp = (const int4*)(interD + (size_t)d0 * RSTRIDE);
#pragma unroll
    for (int k = 0; k < 5; ++k) {
      int4 r4 = rp[k];
      r0[(k << 2) + 0] = r4.x; r0[(k << 2) + 1] = r4.y;
      r0[(k << 2) + 2] = r4.z; r0[(k << 2) + 3] = r4.w;
      cp0 += r4.x + r4.y + r4.z + r4.w;
    }
  }
  if (d1 < n_comp) {
    const int4* rp = (const int4*)(interD + (size_t)d1 * RSTRIDE);
#pragma unroll
    for (int k = 0; k < 5; ++k) {
      int4 r4 = rp[k];
      r1[(k << 2) + 0] = r4.x; r1[(k << 2) + 1] = r4.y;
      r1[(k << 2) + 2] = r4.z; r1[(k << 2) + 3] = r4.w;
      cp1 += r4.x + r4.y + r4.z + r4.w;
    }
  }
  __shared__ unsigned long long wmin[4][16];
  float cf0 = (float)cp0, cf1 = (float)cp1;
  int lane = tid & 63, wv = tid >> 6;
#pragma unroll
  for (int t = 1; t <= TMAX; ++t) {
    unsigned long long key = ~0ULL;
    float ctf = (float)sc->cnt_t[t];
    if (d0 < n_comp) {
      float loss = pair_loss(cf0, (float)r0[t], ctf);
      key = ((unsigned long long)__float_as_uint(loss) << 32) | (unsigned)d0;
    }
    if (d1 < n_comp) {
      float loss = pair_loss(cf1, (float)r1[t], ctf);
      unsigned long long k2 = ((unsigned long long)__float_as_uint(loss) << 32) | (unsigned)d1;
      if (k2 < key) key = k2;
    }
    for (int o = 32; o > 0; o >>= 1) {
      unsigned long long kk = __shfl_down(key, o);
      if (kk < key) key = kk;
    }
    if (!lane) wmin[wv][t - 1] = key;
  }
  __syncthreads();
  if (tid < 16) {
    unsigned long long m = wmin[0][tid];
    if (wmin[1][tid] < m) m = wmin[1][tid];
    if (wmin[2][tid] < m) m = wmin[2][tid];
    if (wmin[3][tid] < m) m = wmin[3][tid];
    bm[(size_t)tid * SMB + blockIdx.x] = m;
  }
}

// ---- k_greedy: 16 waves, redundant wave-synchronous greedy over LDS mins ----
__global__ __launch_bounds__(1024) void k_greedy(const Scalars* __restrict__ sc,
                                                 const int* __restrict__ interD,
                                                 const unsigned long long* __restrict__ bm,
                                                 float* __restrict__ out) {
  __shared__ unsigned long long lbm[16 * SMB];    // 32 KiB
  int tid = threadIdx.x;
  int lane = tid & 63;
#pragma unroll
  for (int k = 0; k < 4; ++k) lbm[tid + (k << 10)] = bm[tid + (k << 10)];
  __syncthreads();

  int n_comp = sc->n_comp;
  if (n_comp > CAP) n_comp = CAP;
  double acc = 0.0;
  int matched = 0, un = 0, nused = 0;
  int used_reg = -1;            // per-wave: lane u (u<nused) holds u-th used id

  for (int t = 1; t <= TMAX; ++t) {
    int ct = sc->cnt_t[t];
    if (ct == 0) continue;
    const int rowoff = (t - 1) * SMB;
    for (int iter = 0; iter < 40; ++iter) {
      unsigned long long key = lbm[rowoff + lane];
#pragma unroll
      for (int k = 1; k < 4; ++k) {
        unsigned long long kk = lbm[rowoff + lane + (k << 6)];
        if (kk < key) key = kk;
      }
      for (int o = 32; o > 0; o >>= 1) {
        unsigned long long kk = __shfl_xor(key, o);
        if (kk < key) key = kk;
      }
      if (key == ~0ULL) { un += 1; break; }
      int dd = (int)(key & 0xFFFFFFFFu);
      bool ex = false;
      for (int u = 0; u < nused; ++u) {
        int uid = __shfl(used_reg, u);
        if (uid == dd) { ex = true; break; }
      }
      if (!ex) {
        acc += (double)__uint_as_float((unsigned)(key >> 32));
        matched += 1;
        if (lane == nused) used_reg = dd;
        nused += 1;
        break;
      }
      // retry: rebuild block b's min (512 comps, 8/lane), excluding used comps
      int b = dd >> 9;
      unsigned long long nk = ~0ULL;
#pragma unroll
      for (int k = 0; k < 8; ++k) {
        int d2 = (b << 9) + lane + (k << 6);
        if (d2 < n_comp) {
          bool ex2 = false;
          for (int u = 0; u < nused; ++u) {
            int uid = __shfl(used_reg, u);
            if (uid == d2) { ex2 = true; break; }
          }
          if (!ex2) {
            const int* rrow = interD + (size_t)d2 * RSTRIDE;
            int c = 0;
#pragma unroll
            for (int j = 0; j < RSTRIDE; ++j) c += rrow[j];
            float loss = pair_loss((float)c, (float)rrow[t], (float)ct);
            unsigned long long cand = ((unsigned long long)__float_as_uint(loss) << 32) | (unsigned)d2;
            if (cand < nk) nk = cand;
          }
        }
      }
      for (int o = 32; o > 0; o >>= 1) {
        unsigned long long kk = __shfl_xor(nk, o);
        if (kk < nk) nk = kk;
      }
      __syncthreads();            // all reads of row complete before rewrite
      if (!tid) lbm[rowoff + b] = nk;
      __syncthreads();            // write visible before next iteration
    }
  }

  if (!tid) {
    double Nd = (double)NPIX;
    double res = sc->sums[0] / Nd
               + 1.0 - (2.0 * sc->sums[2] + 1.0) / (sc->sums[1] + sc->sums[3] + 1.0);
    out[0] = (float)(res + acc + (double)(n_comp - matched) + (double)un);
  }
}

extern "C" void kernel_launch(void* const* d_in, const int* in_sizes, int n_in,
                              void* d_out, int out_size, void* d_ws, size_t ws_size,
                              hipStream_t stream) {
  (void)in_sizes; (void)n_in; (void)out_size; (void)ws_size;
  const float* pred = (const float*)d_in[0];
  const int* tgt = (const int*)d_in[1];
  float* out = (float*)d_out;

  char* w = (char*)d_ws;
  int* P     = (int*)w;            w += (size_t)NPIX * 4;     // parents -> roots
  int* dof   = (int*)w;            w += (size_t)NPIX * 4;     // dense id at roots
  double* part = (double*)w;       w += (size_t)NBLK * NPART * 8;
  Scalars* sc = (Scalars*)w;       w += 256;
  int* bcnt  = (int*)w;            w += 4096;                 // 1024 ints
  unsigned long long* bm = (unsigned long long*)w; w += (size_t)16 * SMB * 8;
  int* interD = (int*)w;           // CAP * RSTRIDE * 4 = 10.5 MB

  k_tile<<<NBLK, 256, 0, stream>>>(pred, tgt, P, part, interD);
  k_border<<<BORDER_BLOCKS, 256, 0, stream>>>(P, part, sc);
  k_flatb<<<NBLK, 256, 0, stream>>>(P, bcnt);
  k_scatter<<<NBLK, 256, 0, stream>>>(P, bcnt, dof, sc);
  k_interall<<<NBLK, 256, 0, stream>>>(P, tgt, dof, interD);
  k_scanmins<<<SMB, 256, 0, stream>>>(sc, interD, bm);
  k_greedy<<<1, 1024, 0, stream>>>(sc, interD, bm, out);
}